// Round 3
// baseline (15165.540 us; speedup 1.0000x reference)
//
#include <hip/hip_runtime.h>
#include <hip/hip_bf16.h>
#include <stdint.h>

#define DIMS 2048
#define SEQ  4096
#define NBLK 128   // persistent blocks for the recurrence
#define RPB  16    // rows of W_hh per block (NBLK*RPB == DIMS)

typedef unsigned long long ull;

// ---------- helpers ----------
__device__ __forceinline__ unsigned pk_bf16(float a, float b) {
  unsigned ua = __float_as_uint(a);
  ua += 0x7fffu + ((ua >> 16) & 1u);
  unsigned ub = __float_as_uint(b);
  ub += 0x7fffu + ((ub >> 16) & 1u);
  return (ua >> 16) | (ub & 0xffff0000u);
}
__device__ __forceinline__ float bflo(unsigned u) { return __uint_as_float(u << 16); }
__device__ __forceinline__ float bfhi(unsigned u) { return __uint_as_float(u & 0xffff0000u); }

// ---------- Kernel A: Z = X @ W_hi^T + b  (fp32, written into d_out) ----------
__global__ __launch_bounds__(256) void gemm_z(const float* __restrict__ X,
                                              const float* __restrict__ W,
                                              const float* __restrict__ bias,
                                              float* __restrict__ Z) {
  __shared__ float xs[64][33];
  __shared__ float ws[64][33];
  const int tid = threadIdx.x;
  const int tx = tid & 15;
  const int ty = tid >> 4;
  const int s0 = blockIdx.x * 64;
  const int d0 = blockIdx.y * 64;

  float acc[4][4] = {};

  for (int k0 = 0; k0 < DIMS; k0 += 32) {
#pragma unroll
    for (int i = 0; i < 2; ++i) {
      int idx = tid + i * 256;
      int r = idx >> 3;
      int c = (idx & 7) << 2;
      float4 xv = *(const float4*)&X[(size_t)(s0 + r) * DIMS + k0 + c];
      xs[r][c] = xv.x; xs[r][c + 1] = xv.y; xs[r][c + 2] = xv.z; xs[r][c + 3] = xv.w;
      float4 wv = *(const float4*)&W[(size_t)(d0 + r) * DIMS + k0 + c];
      ws[r][c] = wv.x; ws[r][c + 1] = wv.y; ws[r][c + 2] = wv.z; ws[r][c + 3] = wv.w;
    }
    __syncthreads();
#pragma unroll
    for (int k = 0; k < 32; ++k) {
      float a_[4], b_[4];
#pragma unroll
      for (int i = 0; i < 4; ++i) a_[i] = xs[ty * 4 + i][k];
#pragma unroll
      for (int j = 0; j < 4; ++j) b_[j] = ws[tx * 4 + j][k];
#pragma unroll
      for (int i = 0; i < 4; ++i)
#pragma unroll
        for (int j = 0; j < 4; ++j) acc[i][j] += a_[i] * b_[j];
    }
    __syncthreads();
  }

  const float4 bv = *(const float4*)&bias[d0 + tx * 4];
#pragma unroll
  for (int i = 0; i < 4; ++i) {
    float4 o;
    o.x = acc[i][0] + bv.x; o.y = acc[i][1] + bv.y;
    o.z = acc[i][2] + bv.z; o.w = acc[i][3] + bv.w;
    *(float4*)&Z[(size_t)(s0 + ty * 4 + i) * DIMS + d0 + tx * 4] = o;
  }
}

// ---------- Kernel B: persistent recurrence with TAGGED h protocol ----------
// hb: 2 slots x DIMS of (fp32 value | tag<<32). Producer at step t publishes
// its 16 h values with tag t+1 into slot (t&1). Consumer at step t polls its
// 8 words of slot ((t+1)&1) until tag == t. No flags, no flag round-trip.
// Safety: slot (t&1) is only overwritten at t+2 after the writer observed all
// tag-(t+2) words, which (by data dependence through the matvec) implies every
// block finished reading the tag-t values. Exact-match polling cannot deadlock.
__global__ __launch_bounds__(256) void rnn_seq(const float* __restrict__ X,
                                               const float* __restrict__ Whh,
                                               const float* __restrict__ h0,
                                               float* __restrict__ ZO,   // d_out: Z in, out overwrites
                                               ull* __restrict__ hb)     // ws: 2*DIMS tagged words
{
  __shared__ uint4  w16[16][RPB][16];  // [j4][row][kk]
  __shared__ float4 hs4[DIMS / 4];     // swizzled h_{t-1}

  const int tid = threadIdx.x;
  const int b   = blockIdx.x;
  const int r   = tid >> 4;            // 0..15
  const int kk  = tid & 15;            // 0..15
  const int grow = b * RPB + r;

  // ---- one-time: pack W_hh rows into LDS as bf16 pairs ----
  {
    const float* wrow = Whh + (size_t)grow * DIMS + kk * 128;
#pragma unroll 4
    for (int j4 = 0; j4 < 16; ++j4) {
      float4 f0 = *(const float4*)(wrow + j4 * 8);
      float4 f1 = *(const float4*)(wrow + j4 * 8 + 4);
      w16[j4][r][kk] = make_uint4(pk_bf16(f0.x, f0.y), pk_bf16(f0.z, f0.w),
                                  pk_bf16(f1.x, f1.y), pk_bf16(f1.z, f1.w));
    }
  }
  // ---- publish h0 slice into slot 1 with tag 0 ----
  if (tid < RPB) {
    ull p = (ull)__float_as_uint(h0[b * RPB + tid]);   // tag 0 in high word
    __hip_atomic_store(&hb[DIMS + b * RPB + tid], p,
                       __ATOMIC_RELAXED, __HIP_MEMORY_SCOPE_AGENT);
  }
  // prefetch Z[0][grow], X[0][grow]
  float zpre = 0.f, xpre = 0.f;
  if (kk == 0) {
    zpre = ZO[grow];
    xpre = X[grow];
  }

  for (int t = 0; t < SEQ; ++t) {
    // ---- poll own 8 tagged words (elements [8*tid, 8*tid+8) of h_{t-1}) ----
    const ull* src = hb + ((size_t)((t + 1) & 1)) * DIMS + tid * 8;
    const int want = t;
    ull v[8];
#pragma unroll
    for (int i = 0; i < 8; ++i)
      v[i] = __hip_atomic_load(src + i, __ATOMIC_RELAXED, __HIP_MEMORY_SCOPE_AGENT);
    for (;;) {
      bool ok = true;
#pragma unroll
      for (int i = 0; i < 8; ++i) {
        if ((int)(v[i] >> 32) != want) {
          ok = false;
          v[i] = __hip_atomic_load(src + i, __ATOMIC_RELAXED, __HIP_MEMORY_SCOPE_AGENT);
        }
      }
      if (ok) break;
    }
    // ---- stage to LDS (swizzled): logical float4 indices 2*tid, 2*tid+1 ----
    {
      float4 A, B;
      A.x = __uint_as_float((unsigned)v[0]); A.y = __uint_as_float((unsigned)v[1]);
      A.z = __uint_as_float((unsigned)v[2]); A.w = __uint_as_float((unsigned)v[3]);
      B.x = __uint_as_float((unsigned)v[4]); B.y = __uint_as_float((unsigned)v[5]);
      B.z = __uint_as_float((unsigned)v[6]); B.w = __uint_as_float((unsigned)v[7]);
      const int key = r & 7;   // group index of these float4s is r
      hs4[r * 32 + ((2 * kk)     ^ key)] = A;
      hs4[r * 32 + ((2 * kk + 1) ^ key)] = B;
    }
    __syncthreads();

    // ---- matvec: row `grow`, K-chunk kk ----
    float acc = 0.f;
#pragma unroll
    for (int j4 = 0; j4 < 16; ++j4) {
      uint4 w = w16[j4][r][kk];
      float4 ha = hs4[kk * 32 + ((2 * j4)     ^ (kk & 7))];
      float4 hc = hs4[kk * 32 + ((2 * j4 + 1) ^ (kk & 7))];
      acc += bflo(w.x) * ha.x + bfhi(w.x) * ha.y + bflo(w.y) * ha.z + bfhi(w.y) * ha.w;
      acc += bflo(w.z) * hc.x + bfhi(w.z) * hc.y + bflo(w.w) * hc.z + bfhi(w.w) * hc.w;
    }
#pragma unroll
    for (int off = 8; off > 0; off >>= 1) acc += __shfl_xor(acc, off, 16);

    if (kk == 0) {
      float y = acc + zpre;
      float hcur = tanhf(y);
      // publish FIRST (critical path for all other blocks)
      ull p = (ull)__float_as_uint(hcur) | ((ull)(unsigned)(t + 1) << 32);
      __hip_atomic_store(&hb[((size_t)(t & 1)) * DIMS + grow], p,
                         __ATOMIC_RELAXED, __HIP_MEMORY_SCOPE_AGENT);
      // then residual output + next-step prefetch (off critical path)
      ZO[(size_t)t * DIMS + grow] = xpre + hcur;
      if (t + 1 < SEQ) {
        zpre = ZO[(size_t)(t + 1) * DIMS + grow];
        xpre = X[(size_t)(t + 1) * DIMS + grow];
      }
    }
    __syncthreads();   // hs4 consume complete before next step's staging
  }
}

// ---------- launch ----------
extern "C" void kernel_launch(void* const* d_in, const int* in_sizes, int n_in,
                              void* d_out, int out_size, void* d_ws, size_t ws_size,
                              hipStream_t stream) {
  (void)in_sizes; (void)n_in; (void)out_size; (void)ws_size;
  const float* X    = (const float*)d_in[0];
  const float* Whi  = (const float*)d_in[1];
  const float* Whh  = (const float*)d_in[2];
  const float* bias = (const float*)d_in[3];
  const float* h0   = (const float*)d_in[4];
  float* out = (float*)d_out;

  ull* hb = (ull*)d_ws;   // 2*DIMS tagged words = 32 KB

  // tags = 0xFFFFFFFF (negative) can never match a wanted tag -> replay-safe
  hipMemsetAsync(hb, 0xFF, 2 * DIMS * sizeof(ull), stream);

  dim3 g(SEQ / 64, DIMS / 64);
  gemm_z<<<g, 256, 0, stream>>>(X, Whi, bias, out);
  rnn_seq<<<NBLK, 256, 0, stream>>>(X, Whh, h0, out, hb);
}